// Round 12
// baseline (300.982 us; speedup 1.0000x reference)
//
#include <hip/hip_runtime.h>
#include <stdint.h>
#include <float.h>

#define HW 160
#define PP 25600
#define BB 8
#define CCH 256
#define NIMG 16
#define LIM 20
#define CPG 32
#define NCG (CCH/CPG)   // 8 channel groups
#define ROWS 8
#define RT (HW/ROWS)    // 20 row tiles
#define NPT 25          // pixels per thread in kccl (PP/1024)

typedef unsigned char u8;
typedef unsigned long long u64;

// ---------------- zero small scratch ----------------
__global__ void kzero(float* binsA, float* binsB, int* cnts,
                      double* sumA, double* sumB, int* lcnt){
  int i = blockIdx.x*256 + threadIdx.x;
  if(i < BB*40*CCH){ binsA[i]=0.f; binsB[i]=0.f; }
  if(i < BB*40) cnts[i]=0;
  if(i < CCH){ sumA[i]=0.0; sumB[i]=0.0; }
  if(i < BB) lcnt[i]=0;
}

__device__ __forceinline__ void gload16(const float* g, float* l){
  __builtin_amdgcn_global_load_lds((const __attribute__((address_space(1))) void*)g,
                                   (__attribute__((address_space(3))) void*)l, 16, 0, 0);
}

// ---------------- conv partial (f32, async global->LDS DMA double-buffer) + x sums ----------------
__global__ __launch_bounds__(256) void kconv(const float* __restrict__ x,
                                             const float* __restrict__ w,
                                             float* __restrict__ partial,
                                             double* __restrict__ sumA,
                                             double* __restrict__ sumB){
  const int b = blockIdx.z, cg = blockIdx.y, bx = blockIdx.x, r0 = bx*ROWS;
  const int tid = threadIdx.x;
  __shared__ float wl[CPG][28];
  __shared__ float xt[2][1600];       // [10 rows][160 cols], linear (row stride 160)
  __shared__ float bsA[CPG][4], bsB[CPG][4];
  for(int t=tid; t<CPG*27; t+=256){
    int cc=t/27, k=t%27;
    wl[cc][k] = w[((k/9)*CCH + cg*CPG + cc)*9 + (k%9)];
  }
  for(int i=tid; i<2*1600; i+=256) ((float*)xt)[i]=0.f;   // boundary rows stay zero
  if(tid<CPG*4){ ((float*)bsA)[tid]=0.f; ((float*)bsB)[tid]=0.f; }

  int src_row = r0 - 1, ldsoff = 0, nchunks = 400;   // 16B chunks
  if(bx == 0){ src_row = 0; ldsoff = 160; nchunks = 360; }
  if(bx == RT-1){ nchunks = 360; }                   // top halo row absent -> tile row 9 stays 0
  const float* xg = x + ((size_t)b*CCH + cg*CPG)*PP;
  const int wid = tid>>6, lane = tid&63;
  const int ch0 = wid*64 + lane, ch1 = 256 + wid*64 + lane;

  #define STAGE(bsel, cc_) { \
    const float* gsrc = xg + (size_t)(cc_)*PP + src_row*HW; \
    if(ch0 < nchunks) gload16(gsrc + ch0*4, &xt[bsel][ldsoff + wid*256]); \
    if(ch1 < nchunks) gload16(gsrc + ch1*4, &xt[bsel][ldsoff + 1024 + wid*256]); }

  const int or_ = tid>>5, j0 = (tid&31)*5;

  __syncthreads();                  // zero-init + weights visible
  STAGE(0, 0);
  __syncthreads();                  // ch0 staged (vmcnt drained at barrier)

  float acc[3][5];
  #pragma unroll
  for(int o=0;o<3;o++)
    #pragma unroll
    for(int px=0;px<5;px++) acc[o][px]=0.f;

  int cur=0;
  for(int cc=0; cc<CPG; cc++){
    if(cc+1<CPG) STAGE(cur^1, cc+1);         // async DMA into other buffer
    float sv[3][7];
    #pragma unroll
    for(int rr=0;rr<3;rr++){
      const float* row = &xt[cur][(or_+rr)*HW];
      sv[rr][0] = (j0>0) ? row[j0-1] : 0.f;
      #pragma unroll
      for(int k=1;k<6;k++) sv[rr][k] = row[j0-1+k];
      sv[rr][6] = (j0+5<HW) ? row[j0+5] : 0.f;   // col 160 would wrap to next row
    }
    float s=0.f, s2=0.f;
    #pragma unroll
    for(int k=1;k<6;k++){ float vv=sv[1][k]; s+=vv; s2=fmaf(vv,vv,s2); }
    #pragma unroll
    for(int off=32; off; off>>=1){ s += __shfl_xor(s,off); s2 += __shfl_xor(s2,off); }
    if(lane==0){ bsA[cc][wid] += s; bsB[cc][wid] += s2; }
    #pragma unroll
    for(int o=0;o<3;o++){
      #pragma unroll
      for(int kr=0;kr<3;kr++){
        float w0 = wl[cc][o*9+kr*3+0];
        float w1 = wl[cc][o*9+kr*3+1];
        float w2 = wl[cc][o*9+kr*3+2];
        #pragma unroll
        for(int px=0;px<5;px++)
          acc[o][px] = fmaf(w0, sv[kr][px], fmaf(w1, sv[kr][px+1], fmaf(w2, sv[kr][px+2], acc[o][px])));
      }
    }
    __syncthreads();                // DMA for cc+1 landed; all reads of cur done
    cur ^= 1;
  }
  #undef STAGE

  if(tid < CPG){
    float a = bsA[tid][0]+bsA[tid][1]+bsA[tid][2]+bsA[tid][3];
    float bq = bsB[tid][0]+bsB[tid][1]+bsB[tid][2]+bsB[tid][3];
    atomicAdd(&sumA[cg*CPG+tid], (double)a);
    atomicAdd(&sumB[cg*CPG+tid], (double)bq);
  }
  size_t base = ((size_t)(cg*BB+b)*3)*PP + (size_t)(r0+or_)*HW + j0;
  #pragma unroll
  for(int o=0;o<3;o++){
    #pragma unroll
    for(int px=0;px<5;px++) partial[base + (size_t)o*PP + px] = acc[o][px];
  }
}

// ---------------- softmax + argmax ----------------
__global__ void ksoftmax(const float* __restrict__ partial, const float* __restrict__ cb,
                         float* __restrict__ attn, u8* __restrict__ am){
  int idx = blockIdx.x*256 + threadIdx.x;
  if(idx >= BB*PP) return;
  int b = idx/PP, p = idx%PP;
  float l[3];
  #pragma unroll
  for(int o=0;o<3;o++){
    float s = cb[o];
    #pragma unroll
    for(int cg=0;cg<NCG;cg++) s += partial[(((size_t)cg*BB+b)*3+o)*PP + p];
    l[o]=s;
  }
  int a=0; float best=l[0];
  if(l[1]>best){best=l[1];a=1;}
  if(l[2]>best){best=l[2];a=2;}
  float e0=__expf(l[0]-best);
  float e1=__expf(l[1]-best);
  float e2=__expf(l[2]-best);
  float inv = 1.f/(e0+e1+e2);
  attn[((size_t)b*3+0)*PP+p]=e0*inv;
  attn[((size_t)b*3+1)*PP+p]=e1*inv;
  attn[((size_t)b*3+2)*PP+p]=e2*inv;
  am[idx]=(u8)a;
}

// ---------------- full CCL in LDS: union-find + select + seg (one block per image) ----------------
__device__ inline int froot(int* par, int x){
  while(true){
    int p = par[x];
    if(p == x) return x;
    int g = par[p];
    if(g == p) return p;
    par[x] = g;   // path halving (benign race)
    x = g;
  }
}
__device__ inline void unite(int* par, int a, int b){
  int ra = froot(par,a), rb = froot(par,b);
  while(ra != rb){
    if(ra > rb){ int t=ra; ra=rb; rb=t; }
    int old = atomicCAS(&par[rb], rb, ra);
    if(old == rb) return;
    rb = froot(par, old);
    ra = froot(par, ra);
  }
}

__global__ __launch_bounds__(1024) void kccl(const u8* __restrict__ am,
                                             u8* __restrict__ seg, int* __restrict__ cnts,
                                             int* __restrict__ list, int* __restrict__ lcnt,
                                             int* __restrict__ nsel){
  __shared__ int par[PP];            // 100 KB
  __shared__ int rootkeys[PP/2];     // 51.2 KB (<= 12800 roots possible)
  __shared__ int redbuf[16];
  __shared__ int selr_s[LIM];
  __shared__ int cntl[LIM];
  __shared__ int nrk, bigcnt, bval;
  const int img = blockIdx.x, b = img>>1, m = (img&1)+1;
  const int tid = threadIdx.x, lane = tid&63, wv = tid>>6;
  const u8* amb = am + b*PP;

  if(tid==0) nrk = 0;
  if(tid<LIM) cntl[tid] = 0;
  // 1. init + masked count
  int mcnt = 0;
  #pragma unroll
  for(int i=0;i<NPT;i++){
    int p = tid + i*1024;
    bool in = (amb[p]==m);
    par[p] = in ? p : -1;
    mcnt += in;
  }
  #pragma unroll
  for(int off=32; off; off>>=1) mcnt += __shfl_xor(mcnt, off);
  if(lane==0) redbuf[wv] = mcnt;
  __syncthreads();
  if(tid==0){ int s=0; for(int i=0;i<16;i++) s+=redbuf[i]; bigcnt=s; }
  __syncthreads();
  const int K = LIM - (bigcnt < PP ? 1 : 0);
  // 2. union (4-connectivity; right+down edges)
  #pragma unroll
  for(int i=0;i<NPT;i++){
    int p = tid + i*1024;
    if(par[p] < 0) continue;
    int j = p % HW;
    if(j < HW-1 && par[p+1] >= 0) unite(par, p, p+1);
    if(p+HW < PP && par[p+HW] >= 0) unite(par, p, p+HW);
  }
  __syncthreads();
  // 3. flatten; cache roots in registers
  int rloc[NPT];
  #pragma unroll
  for(int i=0;i<NPT;i++){
    int p = tid + i*1024;
    int v = par[p];
    if(v < 0){ rloc[i] = -1; continue; }
    int r = froot(par, p);
    par[p] = r;
    rloc[i] = r;
  }
  __syncthreads();
  // 4. fold maxidx into par[root] (root = component min index, so all p >= root;
  //    afterwards p is root <=> par[p] >= p)
  #pragma unroll
  for(int i=0;i<NPT;i++){
    int p = tid + i*1024;
    if(rloc[i] >= 0) atomicMax(&par[rloc[i]], p);
  }
  __syncthreads();
  // 5. compact root keys (maxidx<<16 | root)
  #pragma unroll
  for(int i=0;i<NPT;i++){
    int p = tid + i*1024;
    int v = par[p];
    if(v >= p && v >= 0){
      int pos = atomicAdd(&nrk, 1);
      rootkeys[pos] = (v<<16) | p;
    }
  }
  __syncthreads();
  const int nr = nrk;
  // 6. select K smallest keys
  int prev = -1, n = 0;
  for(int k=0;k<K;k++){
    int best = 0x7fffffff;
    for(int q=tid; q<nr; q+=1024){
      int v = rootkeys[q];
      if(v > prev && v < best) best = v;
    }
    #pragma unroll
    for(int off=32; off; off>>=1){ int o = __shfl_xor(best, off); if(o < best) best = o; }
    if(lane==0) redbuf[wv] = best;
    __syncthreads();
    if(tid==0){ int s=redbuf[0]; for(int i=1;i<16;i++) if(redbuf[i]<s) s=redbuf[i]; bval=s; }
    __syncthreads();
    int bv = bval;
    if(bv == 0x7fffffff) break;
    if(tid==0) selr_s[n] = bv & 0xffff;
    prev = bv; n = k+1;
  }
  __syncthreads();
  // 7. seg codes + counts + selected-pixel list
  #pragma unroll
  for(int i=0;i<NPT;i++){
    int p = tid + i*1024;
    int a = amb[p];
    if(m==1 && a==0){ seg[b*PP+p] = 40; continue; }   // m==1 block owns bg pixels
    if(a != m) continue;                               // other mask's block writes it
    int v = par[p];
    int r = (v >= p) ? p : v;
    int code = LIM;
    for(int k=0;k<n;k++) if(selr_s[k]==r){ code=k; break; }
    if(code < LIM){
      atomicAdd(&cntl[code], 1);
      int gc = (m-1)*LIM + code;
      int pos = atomicAdd(&lcnt[b], 1);
      list[b*PP + pos] = (gc<<16) | p;
      seg[b*PP+p] = (u8)gc;
    } else {
      seg[b*PP+p] = 40;
    }
  }
  __syncthreads();
  if(tid < n) cnts[b*40 + (m-1)*LIM + tid] = cntl[tid];
  if(tid==0) nsel[img] = n;
}

// ---------------- gather bins for selected pixels only ----------------
__global__ __launch_bounds__(256) void kbins2(const float* __restrict__ x, const int* __restrict__ list,
                                              const int* __restrict__ lcnt,
                                              float* __restrict__ binsA, float* __restrict__ binsB){
  const int b = blockIdx.y;
  const int n = lcnt[b];
  const int c = threadIdx.x;
  for(int e = blockIdx.x; e < n; e += gridDim.x){
    int ent = list[b*PP + e];
    int p = ent & 0xffff;
    int code = ent >> 16;
    float v = x[((size_t)b*CCH + c)*PP + p];
    atomicAdd(&binsA[((size_t)b*40 + code)*CCH + c], v);
    atomicAdd(&binsB[((size_t)b*40 + code)*CCH + c], v*v);
  }
}

// ---------------- per-batch M = m1 m2^T, factors (f64 magnitude-faithful) ----------------
__global__ __launch_bounds__(256) void kmult(const float* __restrict__ binsA, const int* __restrict__ cnts,
                       const int* __restrict__ nsel, double* __restrict__ multd,
                       float* __restrict__ multf){
  const int b = blockIdx.x, t = threadIdx.x;
  __shared__ float m1[LIM][CCH+1], m2[LIM][CCH+1];
  __shared__ float Ml[LIM*LIM];
  const int n1 = nsel[b*2+0], n2 = nsel[b*2+1];
  for(int k=0;k<LIM;k++){
    m1[k][t] = (k<n1) ? binsA[((size_t)b*40 + k)*CCH + t] / (float)cnts[b*40 + k] : 0.f;
    m2[k][t] = (k<n2) ? binsA[((size_t)b*40 + LIM + k)*CCH + t] / (float)cnts[b*40 + LIM + k] : 0.f;
  }
  __syncthreads();
  for(int pid=t; pid<LIM*LIM; pid+=256){
    int i = pid/LIM, j = pid%LIM;
    float d = 0.f;
    for(int c=0;c<CCH;c++) d += m1[i][c]*m2[j][c];
    Ml[pid] = 1.f + d;   // rows/cols for invalid comps are exactly 1
  }
  __syncthreads();
  if(t < LIM){
    double pr=1.0;
    for(int j=0;j<LIM;j++) pr *= (double)Ml[t*LIM+j];
    multd[b*40 + t] = pr;
    multf[b*40 + t] = (float)pr;        // may overflow to inf, like np-f32
  } else if(t>=64 && t<64+LIM){
    int j=t-64; double pr=1.0;
    for(int i=0;i<LIM;i++) pr *= (double)Ml[i*LIM+j];
    multd[b*40 + LIM + j] = pr;
    multf[b*40 + LIM + j] = (float)pr;
  }
}

// ---------------- BN scale/shift with float32-overflow semantics ----------------
__global__ void kscale(const float* __restrict__ binsA, const float* __restrict__ binsB,
                       const double* __restrict__ sumA, const double* __restrict__ sumB,
                       const double* __restrict__ multd, const float* __restrict__ gamma,
                       const float* __restrict__ beta, float* __restrict__ scale, float* __restrict__ shift){
  int c = threadIdx.x;
  double s = sumA[c], s2 = sumB[c];
  for(int b=0;b<BB;b++){
    for(int sc=0; sc<40; sc++){
      double f = multd[b*40+sc];
      s  += (f-1.0)   * (double)binsA[((size_t)b*40+sc)*CCH + c];
      s2 += (f*f-1.0) * (double)binsB[((size_t)b*40+sc)*CCH + c];
    }
  }
  const double N = (double)BB*PP;
  double mean = s/N;
  double devsq = s2 - N*mean*mean;     // = sum((x2 - mu)^2), exact-ish in f64
  bool ovf = !(devsq <= 3.3e38) || !(fabs(s) <= 3.3e38) || !(s2 < 1e300);
  if(ovf){
    scale[c] = 0.f;
    shift[c] = beta[c];
  } else {
    double var = devsq/N;
    double inv = 1.0 / sqrt(var + 1e-5);
    float scv = (float)inv * gamma[c];
    scale[c] = scv;
    shift[c] = beta[c] - (float)mean * scv;
  }
}

// ---------------- final write: out = x*f*scale + shift (scale==0 -> shift) ----------------
__global__ __launch_bounds__(256) void kout(const float* __restrict__ x, const u8* __restrict__ seg,
                      const float* __restrict__ multf, const float* __restrict__ scale,
                      const float* __restrict__ shift, float* __restrict__ out){
  size_t idx = ((size_t)blockIdx.x*256 + threadIdx.x)*4;
  int b = (int)(idx / ((size_t)CCH*PP));
  int c = (int)((idx / PP) % CCH);
  int p = (int)(idx % PP);
  __shared__ float fm[41];
  if(threadIdx.x <= 40) fm[threadIdx.x] = (threadIdx.x<40) ? multf[b*40 + threadIdx.x] : 1.f;
  __syncthreads();
  float sc = scale[c], sh = shift[c];
  float4 o;
  if(sc == 0.f){
    o.x = sh; o.y = sh; o.z = sh; o.w = sh;   // avoid inf*0 = nan
  } else {
    float4 xv = *(const float4*)(x + idx);
    uchar4 sv = *(const uchar4*)(seg + (size_t)b*PP + p);
    o.x = xv.x * fm[sv.x] * sc + sh;
    o.y = xv.y * fm[sv.y] * sc + sh;
    o.z = xv.z * fm[sv.z] * sc + sh;
    o.w = xv.w * fm[sv.w] * sc + sh;
  }
  *(float4*)(out + idx) = o;
}

extern "C" void kernel_launch(void* const* d_in, const int* in_sizes, int n_in,
                              void* d_out, int out_size, void* d_ws, size_t ws_size,
                              hipStream_t stream){
  (void)in_sizes; (void)n_in; (void)out_size; (void)ws_size;
  const float* x  = (const float*)d_in[0];
  const float* w  = (const float*)d_in[1];
  const float* cb = (const float*)d_in[2];
  const float* gamma = (const float*)d_in[3];
  const float* beta  = (const float*)d_in[4];
  float* out  = (float*)d_out;
  float* attn = out + (size_t)BB*CCH*PP;       // 52,428,800

  // big scratch lives in the (not-yet-written) xn region of d_out
  float* partial  = out;                       // 8*8*3*25600 = 4,915,200 floats
  u8*    am       = (u8*)(out + 21000000);     // 204,800 B
  float* binsA    = out + 21100000;            // 8*40*256
  float* binsB    = out + 21200000;
  int*   list     = (int*)(out + 21700000);    // 8*25600 ints
  int*   lcnt     = (int*)(out + 22000000);    // 8 ints
  double* sumA    = (double*)(out + 22100000); // 256 doubles (8B aligned: even float idx)
  double* sumB    = (double*)(out + 22101000);

  // K-kernel inputs live in ws (must survive while kout overwrites d_out)
  double* multd = (double*)d_ws;               // 320 doubles
  float* multf  = (float*)((char*)d_ws + 2560);
  float* scale  = multf + BB*40;
  float* shift  = scale + CCH;
  int* nsel     = (int*)(shift + CCH);
  int* cnts     = nsel + NIMG;
  u8* seg       = (u8*)(cnts + BB*40);         // 204,800 B

  kzero<<<dim3(320), dim3(256), 0, stream>>>(binsA, binsB, cnts, sumA, sumB, lcnt);
  kconv<<<dim3(RT,NCG,BB), dim3(256), 0, stream>>>(x, w, partial, sumA, sumB);
  ksoftmax<<<dim3(800), dim3(256), 0, stream>>>(partial, cb, attn, am);
  kccl<<<dim3(NIMG), dim3(1024), 0, stream>>>(am, seg, cnts, list, lcnt, nsel);
  kbins2<<<dim3(64,BB), dim3(256), 0, stream>>>(x, list, lcnt, binsA, binsB);
  kmult<<<dim3(BB), dim3(256), 0, stream>>>(binsA, cnts, nsel, multd, multf);
  kscale<<<dim3(1), dim3(256), 0, stream>>>(binsA, binsB, sumA, sumB, multd, gamma, beta, scale, shift);
  kout<<<dim3(51200), dim3(256), 0, stream>>>(x, seg, multf, scale, shift, out);
}

// Round 13
// 279.709 us; speedup vs baseline: 1.0761x; 1.0761x over previous
//
#include <hip/hip_runtime.h>
#include <stdint.h>
#include <float.h>

#define HW 160
#define PP 25600
#define BB 8
#define CCH 256
#define NIMG 16
#define LIM 20
#define MAXC 12800
#define CPG 32
#define NCG (CCH/CPG)   // 8 channel groups
#define ROWS 8
#define RT (HW/ROWS)    // 20 row tiles

typedef unsigned char u8;
typedef unsigned long long u64;

// ---------------- zero small scratch ----------------
__global__ void kzero(float* binsA, float* binsB, int* cnts, int* ncomp,
                      double* sumA, double* sumB, int* lcnt){
  int i = blockIdx.x*256 + threadIdx.x;
  if(i < BB*40*CCH){ binsA[i]=0.f; binsB[i]=0.f; }
  if(i < BB*40) cnts[i]=0;
  if(i < NIMG) ncomp[i]=0;
  if(i < CCH){ sumA[i]=0.0; sumB[i]=0.0; }
  if(i < BB) lcnt[i]=0;
}

__device__ __forceinline__ void gload16(const float* g, float* l){
  __builtin_amdgcn_global_load_lds((const __attribute__((address_space(1))) void*)g,
                                   (__attribute__((address_space(3))) void*)l, 16, 0, 0);
}

// ---------------- conv partial (f32, async DMA, 2 channels per buffer) + x sums ----------------
// Block: 8 rows x 160 cols x 32 channels. Per channel the halo tile
// (rows r0-1..r0+8) is ONE contiguous 6400B span of x -> global_load_lds.
// TWO channels staged per buffer: compute phase (~2x) fully covers DMA
// latency and barrier count halves (33 -> 17).
__global__ __launch_bounds__(256) void kconv(const float* __restrict__ x,
                                             const float* __restrict__ w,
                                             float* __restrict__ partial,
                                             double* __restrict__ sumA,
                                             double* __restrict__ sumB){
  const int b = blockIdx.z, cg = blockIdx.y, bx = blockIdx.x, r0 = bx*ROWS;
  const int tid = threadIdx.x;
  __shared__ float wl[CPG][28];
  __shared__ float xt[2][3200];       // 2 channels x [10 rows][160 cols] linear
  __shared__ float bsA[CPG][4], bsB[CPG][4];
  for(int t=tid; t<CPG*27; t+=256){
    int cc=t/27, k=t%27;
    wl[cc][k] = w[((k/9)*CCH + cg*CPG + cc)*9 + (k%9)];
  }
  for(int i=tid; i<2*3200; i+=256) ((float*)xt)[i]=0.f;   // boundary rows stay zero
  if(tid<CPG*4){ ((float*)bsA)[tid]=0.f; ((float*)bsB)[tid]=0.f; }

  int src_row = r0 - 1, ldsoff = 0, nchunks = 400;   // 16B chunks per channel
  if(bx == 0){ src_row = 0; ldsoff = 160; nchunks = 360; }
  if(bx == RT-1){ nchunks = 360; }                   // top halo row absent -> tile row 9 stays 0
  const float* xg = x + ((size_t)b*CCH + cg*CPG)*PP;
  const int wid = tid>>6, lane = tid&63;
  const int ch0 = wid*64 + lane, ch1 = 256 + wid*64 + lane;

  #define STAGE(bsel, ccp_) { \
    const float* g0 = xg + (size_t)(ccp_)*PP + src_row*HW; \
    const float* g1 = g0 + PP; \
    if(ch0 < nchunks){ gload16(g0 + ch0*4, &xt[bsel][ldsoff + wid*256]); \
                       gload16(g1 + ch0*4, &xt[bsel][1600 + ldsoff + wid*256]); } \
    if(ch1 < nchunks){ gload16(g0 + ch1*4, &xt[bsel][ldsoff + 1024 + wid*256]); \
                       gload16(g1 + ch1*4, &xt[bsel][1600 + ldsoff + 1024 + wid*256]); } }

  const int or_ = tid>>5, j0 = (tid&31)*5;

  __syncthreads();                  // zero-init + weights visible
  STAGE(0, 0);
  __syncthreads();                  // ch0+ch1 staged (vmcnt drained at barrier)

  float acc[3][5];
  #pragma unroll
  for(int o=0;o<3;o++)
    #pragma unroll
    for(int px=0;px<5;px++) acc[o][px]=0.f;

  int cur=0;
  for(int ccp=0; ccp<CPG; ccp+=2){
    if(ccp+2<CPG) STAGE(cur^1, ccp+2);       // async DMA into other buffer
    #pragma unroll
    for(int sub=0; sub<2; sub++){
      const int cc = ccp + sub;
      const float* xb_ = &xt[cur][sub*1600];
      float sv[3][7];
      #pragma unroll
      for(int rr=0;rr<3;rr++){
        const float* row = xb_ + (or_+rr)*HW;
        sv[rr][0] = (j0>0) ? row[j0-1] : 0.f;
        #pragma unroll
        for(int k=1;k<6;k++) sv[rr][k] = row[j0-1+k];
        sv[rr][6] = (j0+5<HW) ? row[j0+5] : 0.f;   // col 160 would wrap to next row
      }
      float s=0.f, s2=0.f;
      #pragma unroll
      for(int k=1;k<6;k++){ float vv=sv[1][k]; s+=vv; s2=fmaf(vv,vv,s2); }
      #pragma unroll
      for(int off=32; off; off>>=1){ s += __shfl_xor(s,off); s2 += __shfl_xor(s2,off); }
      if(lane==0){ bsA[cc][wid] += s; bsB[cc][wid] += s2; }
      #pragma unroll
      for(int o=0;o<3;o++){
        #pragma unroll
        for(int kr=0;kr<3;kr++){
          float w0 = wl[cc][o*9+kr*3+0];
          float w1 = wl[cc][o*9+kr*3+1];
          float w2 = wl[cc][o*9+kr*3+2];
          #pragma unroll
          for(int px=0;px<5;px++)
            acc[o][px] = fmaf(w0, sv[kr][px], fmaf(w1, sv[kr][px+1], fmaf(w2, sv[kr][px+2], acc[o][px])));
        }
      }
    }
    __syncthreads();                // DMA for next pair landed; all reads of cur done
    cur ^= 1;
  }
  #undef STAGE

  if(tid < CPG){
    float a = bsA[tid][0]+bsA[tid][1]+bsA[tid][2]+bsA[tid][3];
    float bq = bsB[tid][0]+bsB[tid][1]+bsB[tid][2]+bsB[tid][3];
    atomicAdd(&sumA[cg*CPG+tid], (double)a);
    atomicAdd(&sumB[cg*CPG+tid], (double)bq);
  }
  size_t base = ((size_t)(cg*BB+b)*3)*PP + (size_t)(r0+or_)*HW + j0;
  #pragma unroll
  for(int o=0;o<3;o++){
    #pragma unroll
    for(int px=0;px<5;px++) partial[base + (size_t)o*PP + px] = acc[o][px];
  }
}

// ---------------- softmax + argmax + union-find init (fused) ----------------
__global__ void ksoftmax(const float* __restrict__ partial, const float* __restrict__ cb,
                         float* __restrict__ attn, u8* __restrict__ am,
                         int* __restrict__ parent, int* __restrict__ maxidx){
  int idx = blockIdx.x*256 + threadIdx.x;
  if(idx >= BB*PP) return;
  int b = idx/PP, p = idx%PP;
  float l[3];
  #pragma unroll
  for(int o=0;o<3;o++){
    float s = cb[o];
    #pragma unroll
    for(int cg=0;cg<NCG;cg++) s += partial[(((size_t)cg*BB+b)*3+o)*PP + p];
    l[o]=s;
  }
  int a=0; float best=l[0];
  if(l[1]>best){best=l[1];a=1;}
  if(l[2]>best){best=l[2];a=2;}
  float e0=__expf(l[0]-best);
  float e1=__expf(l[1]-best);
  float e2=__expf(l[2]-best);
  float inv = 1.f/(e0+e1+e2);
  attn[((size_t)b*3+0)*PP+p]=e0*inv;
  attn[((size_t)b*3+1)*PP+p]=e1*inv;
  attn[((size_t)b*3+2)*PP+p]=e2*inv;
  am[idx]=(u8)a;
  int i1 = (b*2+0)*PP + p, i2 = (b*2+1)*PP + p;
  parent[i1] = (a==1) ? p : -1;
  parent[i2] = (a==2) ? p : -1;
  maxidx[i1] = -1;
  maxidx[i2] = -1;
}

// ---------------- CCL: union-find ----------------
__device__ inline int froot(int* par, int x){
  while(true){
    int p = par[x];
    if(p == x) return x;
    int g = par[p];
    if(g == p) return p;
    par[x] = g;   // path halving (benign race)
    x = g;
  }
}
__device__ inline void unite(int* par, int a, int b){
  int ra = froot(par,a), rb = froot(par,b);
  while(ra != rb){
    if(ra > rb){ int t=ra; ra=rb; rb=t; }
    int old = atomicCAS(&par[rb], rb, ra);
    if(old == rb) return;
    rb = froot(par, old);
    ra = froot(par, ra);
  }
}
__global__ void kunion(int* parent){
  int idx = blockIdx.x*256 + threadIdx.x;
  if(idx >= NIMG*PP) return;
  int img = idx/PP, p = idx%PP;
  int* par = parent + img*PP;
  if(par[p] < 0) return;
  int i = p/HW, j = p%HW;
  if(j < HW-1 && par[p+1] >= 0) unite(par, p, p+1);
  if(i < HW-1 && par[p+HW] >= 0) unite(par, p, p+HW);
}
// flatten + per-root max flat index (fused)
__global__ void kflatmax(int* parent, int* __restrict__ maxidx){
  int idx = blockIdx.x*256 + threadIdx.x;
  if(idx >= NIMG*PP) return;
  int img = idx/PP, p = idx%PP;
  int* par = parent + img*PP;
  if(par[p] < 0) return;
  int r = froot(par, p);
  par[p] = r;
  atomicMax(&maxidx[img*PP + r], p);
}

// ---------------- compact roots (block-aggregated: 1 atomic per block) ----------------
__global__ void kcompact(const int* __restrict__ parent, const int* __restrict__ maxidx,
                         int* __restrict__ rootlist, int* __restrict__ ncomp){
  int idx = blockIdx.x*256 + threadIdx.x;
  int img = idx/PP, p = idx%PP;                 // block lies in one img (PP%256==0)
  bool isroot = (parent[idx] == p);
  u64 mask = __ballot(isroot);
  int lane = threadIdx.x & 63;
  int wid = threadIdx.x >> 6;
  __shared__ int wcnt[4];
  __shared__ int bbase;
  if(lane == 0) wcnt[wid] = __popcll(mask);
  __syncthreads();
  if(threadIdx.x == 0){
    int tot = wcnt[0]+wcnt[1]+wcnt[2]+wcnt[3];
    bbase = (tot>0) ? atomicAdd(&ncomp[img], tot) : 0;
  }
  __syncthreads();
  if(isroot){
    int mybase = bbase;
    for(int wv=0; wv<wid; wv++) mybase += wcnt[wv];
    mybase += __popcll(mask & ((lane==63)? ~0ull>>1 : ((1ull<<lane)-1)));
    rootlist[img*MAXC + mybase] = (maxidx[idx]<<16) | p;   // sort key: maxidx-major
  }
}

// ---------------- select up to (20 - bg) smallest-label components ----------------
__global__ __launch_bounds__(256) void kselect(const int* __restrict__ rootlist, const int* __restrict__ ncomp,
                        const int* __restrict__ parent,
                        int* __restrict__ selr, int* __restrict__ nsel){
  int img = blockIdx.x, t = threadIdx.x;
  __shared__ int sv[256];
  __shared__ int scnt[256];
  const int* par = parent + img*PP;
  int cnt=0;
  for(int p=t; p<PP; p+=256) cnt += (par[p]>=0) ? 1 : 0;
  scnt[t]=cnt; __syncthreads();
  for(int off=128; off; off>>=1){ if(t<off) scnt[t]+=scnt[t+off]; __syncthreads(); }
  int K = LIM - ((scnt[0] < PP) ? 1 : 0);   // background label 0 takes rank 0 if present
  int nr = ncomp[img];
  const int* rl = rootlist + img*MAXC;
  int prev = -1, n = 0;
  for(int k=0;k<K;k++){
    int best = 0x7fffffff;
    for(int q=t; q<nr; q+=256){ int v=rl[q]; if(v>prev && v<best) best=v; }
    sv[t]=best; __syncthreads();
    for(int off=128; off; off>>=1){
      if(t<off && sv[t+off]<sv[t]) sv[t]=sv[t+off];
      __syncthreads();
    }
    int bv = sv[0]; __syncthreads();
    if(bv == 0x7fffffff) break;
    if(t==0) selr[img*LIM+k] = bv & 0xffff;
    prev = bv; n = k+1;
  }
  if(t==0) nsel[img] = n;
}

// ---------------- per-pixel segment code + counts + selected-pixel list ----------------
__global__ void kseg(const u8* __restrict__ am, const int* __restrict__ parent,
                     const int* __restrict__ selr, const int* __restrict__ nsel,
                     u8* __restrict__ seg, int* __restrict__ cnts,
                     int* __restrict__ list, int* __restrict__ lcnt){
  int idx = blockIdx.x*256 + threadIdx.x;
  __shared__ int cl[40];
  if(threadIdx.x < 40) cl[threadIdx.x] = 0;
  __syncthreads();
  int b = idx/PP, p = idx%PP;
  int a = am[idx];
  int code = 40;
  if(a > 0){
    int img = b*2 + a - 1;
    int r = parent[img*PP + p];
    int n = nsel[img];
    for(int k=0;k<n;k++){
      if(selr[img*LIM + k] == r){ code = (a-1)*LIM + k; break; }
    }
  }
  seg[idx] = (u8)code;
  if(code < 40){
    atomicAdd(&cl[code], 1);
    int pos = atomicAdd(&lcnt[b], 1);
    list[b*PP + pos] = (code<<16) | p;          // p < 25600 < 65536
  }
  __syncthreads();
  if(threadIdx.x < 40 && cl[threadIdx.x] > 0) atomicAdd(&cnts[b*40 + threadIdx.x], cl[threadIdx.x]);
}

// ---------------- gather bins for selected pixels only ----------------
__global__ __launch_bounds__(256) void kbins2(const float* __restrict__ x, const int* __restrict__ list,
                                              const int* __restrict__ lcnt,
                                              float* __restrict__ binsA, float* __restrict__ binsB){
  const int b = blockIdx.y;
  const int n = lcnt[b];
  const int c = threadIdx.x;
  for(int e = blockIdx.x; e < n; e += gridDim.x){
    int ent = list[b*PP + e];
    int p = ent & 0xffff;
    int code = ent >> 16;
    float v = x[((size_t)b*CCH + c)*PP + p];
    atomicAdd(&binsA[((size_t)b*40 + code)*CCH + c], v);
    atomicAdd(&binsB[((size_t)b*40 + code)*CCH + c], v*v);
  }
}

// ---------------- per-batch M = m1 m2^T, factors (f64 magnitude-faithful) ----------------
__global__ __launch_bounds__(256) void kmult(const float* __restrict__ binsA, const int* __restrict__ cnts,
                       const int* __restrict__ nsel, double* __restrict__ multd,
                       float* __restrict__ multf){
  const int b = blockIdx.x, t = threadIdx.x;
  __shared__ float m1[LIM][CCH+1], m2[LIM][CCH+1];
  __shared__ float Ml[LIM*LIM];
  const int n1 = nsel[b*2+0], n2 = nsel[b*2+1];
  for(int k=0;k<LIM;k++){
    m1[k][t] = (k<n1) ? binsA[((size_t)b*40 + k)*CCH + t] / (float)cnts[b*40 + k] : 0.f;
    m2[k][t] = (k<n2) ? binsA[((size_t)b*40 + LIM + k)*CCH + t] / (float)cnts[b*40 + LIM + k] : 0.f;
  }
  __syncthreads();
  for(int pid=t; pid<LIM*LIM; pid+=256){
    int i = pid/LIM, j = pid%LIM;
    float d = 0.f;
    for(int c=0;c<CCH;c++) d += m1[i][c]*m2[j][c];
    Ml[pid] = 1.f + d;   // rows/cols for invalid comps are exactly 1
  }
  __syncthreads();
  if(t < LIM){
    double pr=1.0;
    for(int j=0;j<LIM;j++) pr *= (double)Ml[t*LIM+j];
    multd[b*40 + t] = pr;
    multf[b*40 + t] = (float)pr;        // may overflow to inf, like np-f32
  } else if(t>=64 && t<64+LIM){
    int j=t-64; double pr=1.0;
    for(int i=0;i<LIM;i++) pr *= (double)Ml[i*LIM+j];
    multd[b*40 + LIM + j] = pr;
    multf[b*40 + LIM + j] = (float)pr;
  }
}

// ---------------- BN scale/shift with float32-overflow semantics ----------------
__global__ void kscale(const float* __restrict__ binsA, const float* __restrict__ binsB,
                       const double* __restrict__ sumA, const double* __restrict__ sumB,
                       const double* __restrict__ multd, const float* __restrict__ gamma,
                       const float* __restrict__ beta, float* __restrict__ scale, float* __restrict__ shift){
  int c = threadIdx.x;
  double s = sumA[c], s2 = sumB[c];
  for(int b=0;b<BB;b++){
    for(int sc=0; sc<40; sc++){
      double f = multd[b*40+sc];
      s  += (f-1.0)   * (double)binsA[((size_t)b*40+sc)*CCH + c];
      s2 += (f*f-1.0) * (double)binsB[((size_t)b*40+sc)*CCH + c];
    }
  }
  const double N = (double)BB*PP;
  double mean = s/N;
  double devsq = s2 - N*mean*mean;     // = sum((x2 - mu)^2), exact-ish in f64
  bool ovf = !(devsq <= 3.3e38) || !(fabs(s) <= 3.3e38) || !(s2 < 1e300);
  if(ovf){
    scale[c] = 0.f;
    shift[c] = beta[c];
  } else {
    double var = devsq/N;
    double inv = 1.0 / sqrt(var + 1e-5);
    float scv = (float)inv * gamma[c];
    scale[c] = scv;
    shift[c] = beta[c] - (float)mean * scv;
  }
}

// ---------------- final write: out = x*f*scale + shift (scale==0 -> shift) ----------------
__global__ __launch_bounds__(256) void kout(const float* __restrict__ x, const u8* __restrict__ seg,
                      const float* __restrict__ multf, const float* __restrict__ scale,
                      const float* __restrict__ shift, float* __restrict__ out){
  size_t idx = ((size_t)blockIdx.x*256 + threadIdx.x)*4;
  int b = (int)(idx / ((size_t)CCH*PP));
  int c = (int)((idx / PP) % CCH);
  int p = (int)(idx % PP);
  __shared__ float fm[41];
  if(threadIdx.x <= 40) fm[threadIdx.x] = (threadIdx.x<40) ? multf[b*40 + threadIdx.x] : 1.f;
  __syncthreads();
  float sc = scale[c], sh = shift[c];
  float4 o;
  if(sc == 0.f){
    o.x = sh; o.y = sh; o.z = sh; o.w = sh;   // avoid inf*0 = nan
  } else {
    float4 xv = *(const float4*)(x + idx);
    uchar4 sv = *(const uchar4*)(seg + (size_t)b*PP + p);
    o.x = xv.x * fm[sv.x] * sc + sh;
    o.y = xv.y * fm[sv.y] * sc + sh;
    o.z = xv.z * fm[sv.z] * sc + sh;
    o.w = xv.w * fm[sv.w] * sc + sh;
  }
  *(float4*)(out + idx) = o;
}

extern "C" void kernel_launch(void* const* d_in, const int* in_sizes, int n_in,
                              void* d_out, int out_size, void* d_ws, size_t ws_size,
                              hipStream_t stream){
  (void)in_sizes; (void)n_in; (void)out_size; (void)ws_size;
  const float* x  = (const float*)d_in[0];
  const float* w  = (const float*)d_in[1];
  const float* cb = (const float*)d_in[2];
  const float* gamma = (const float*)d_in[3];
  const float* beta  = (const float*)d_in[4];
  float* out  = (float*)d_out;
  float* attn = out + (size_t)BB*CCH*PP;       // 52,428,800

  // big scratch lives in the (not-yet-written) xn region of d_out
  float* partial  = out;                       // 8*8*3*25600 = 4,915,200 floats
  int*   parent   = (int*)(out + 20000000);    // 409,600 ints
  int*   maxidx   = (int*)(out + 20500000);    // 409,600 ints
  u8*    am       = (u8*)(out + 21000000);     // 204,800 B
  float* binsA    = out + 21100000;            // 8*40*256
  float* binsB    = out + 21200000;
  int*   rootlist = (int*)(out + 21300000);    // 16*12800 ints
  int*   ncomp    = (int*)(out + 21600000);    // 16 ints
  int*   list     = (int*)(out + 21700000);    // 8*25600 ints
  int*   lcnt     = (int*)(out + 22000000);    // 8 ints
  double* sumA    = (double*)(out + 22100000); // 256 doubles (8B aligned: even float idx)
  double* sumB    = (double*)(out + 22101000);

  // K-kernel inputs live in ws (must survive while kout overwrites d_out)
  double* multd = (double*)d_ws;               // 320 doubles
  float* multf  = (float*)((char*)d_ws + 2560);
  float* scale  = multf + BB*40;
  float* shift  = scale + CCH;
  int* selr     = (int*)(shift + CCH);
  int* nsel     = selr + NIMG*LIM;
  int* cnts     = nsel + NIMG;
  u8* seg       = (u8*)(cnts + BB*40);         // 204,800 B

  kzero<<<dim3(320), dim3(256), 0, stream>>>(binsA, binsB, cnts, ncomp, sumA, sumB, lcnt);
  kconv<<<dim3(RT,NCG,BB), dim3(256), 0, stream>>>(x, w, partial, sumA, sumB);
  ksoftmax<<<dim3(800), dim3(256), 0, stream>>>(partial, cb, attn, am, parent, maxidx);
  kunion<<<dim3(1600), dim3(256), 0, stream>>>(parent);
  kflatmax<<<dim3(1600), dim3(256), 0, stream>>>(parent, maxidx);
  kcompact<<<dim3(1600), dim3(256), 0, stream>>>(parent, maxidx, rootlist, ncomp);
  kselect<<<dim3(NIMG), dim3(256), 0, stream>>>(rootlist, ncomp, parent, selr, nsel);
  kseg<<<dim3(800), dim3(256), 0, stream>>>(am, parent, selr, nsel, seg, cnts, list, lcnt);
  kbins2<<<dim3(64,BB), dim3(256), 0, stream>>>(x, list, lcnt, binsA, binsB);
  kmult<<<dim3(BB), dim3(256), 0, stream>>>(binsA, cnts, nsel, multd, multf);
  kscale<<<dim3(1), dim3(256), 0, stream>>>(binsA, binsB, sumA, sumB, multd, gamma, beta, scale, shift);
  kout<<<dim3(51200), dim3(256), 0, stream>>>(x, seg, multf, scale, shift, out);
}

// Round 14
// 267.711 us; speedup vs baseline: 1.1243x; 1.0448x over previous
//
#include <hip/hip_runtime.h>
#include <stdint.h>
#include <float.h>

#define HW 160
#define PP 25600
#define BB 8
#define CCH 256
#define NIMG 16
#define LIM 20
#define MAXC 12800
#define CPG 32
#define NCG (CCH/CPG)   // 8 channel groups
#define ROWS 8
#define RT (HW/ROWS)    // 20 row tiles

typedef unsigned char u8;
typedef unsigned long long u64;

// ---------------- zero small scratch ----------------
__global__ void kzero(float* binsA, float* binsB, int* cnts, int* ncomp,
                      double* sumA, double* sumB, int* lcnt){
  int i = blockIdx.x*256 + threadIdx.x;
  if(i < BB*40*CCH){ binsA[i]=0.f; binsB[i]=0.f; }
  if(i < BB*40) cnts[i]=0;
  if(i < NIMG) ncomp[i]=0;
  if(i < CCH){ sumA[i]=0.0; sumB[i]=0.0; }
  if(i < BB) lcnt[i]=0;
}

__device__ __forceinline__ void gload16(const float* g, float* l){
  __builtin_amdgcn_global_load_lds((const __attribute__((address_space(1))) void*)g,
                                   (__attribute__((address_space(3))) void*)l, 16, 0, 0);
}

// ---------------- conv partial (f32, async global->LDS DMA double-buffer) + x sums ----------------
// Round-11 configuration (measured best: 272 us total). One channel per LDS
// buffer; per channel the halo tile (rows r0-1..r0+8) is ONE contiguous
// 6400B span of x -> global_load_lds_dwordx4, linear LDS [10][160].
// Right-edge halo (col 160) handled in registers (linear tile has no col pad).
__global__ __launch_bounds__(256) void kconv(const float* __restrict__ x,
                                             const float* __restrict__ w,
                                             float* __restrict__ partial,
                                             double* __restrict__ sumA,
                                             double* __restrict__ sumB){
  const int b = blockIdx.z, cg = blockIdx.y, bx = blockIdx.x, r0 = bx*ROWS;
  const int tid = threadIdx.x;
  __shared__ float wl[CPG][28];
  __shared__ float xt[2][1600];       // [10 rows][160 cols], linear (row stride 160)
  __shared__ float bsA[CPG][4], bsB[CPG][4];
  for(int t=tid; t<CPG*27; t+=256){
    int cc=t/27, k=t%27;
    wl[cc][k] = w[((k/9)*CCH + cg*CPG + cc)*9 + (k%9)];
  }
  for(int i=tid; i<2*1600; i+=256) ((float*)xt)[i]=0.f;   // boundary rows stay zero
  if(tid<CPG*4){ ((float*)bsA)[tid]=0.f; ((float*)bsB)[tid]=0.f; }

  int src_row = r0 - 1, ldsoff = 0, nchunks = 400;   // 16B chunks
  if(bx == 0){ src_row = 0; ldsoff = 160; nchunks = 360; }
  if(bx == RT-1){ nchunks = 360; }                   // top halo row absent -> tile row 9 stays 0
  const float* xg = x + ((size_t)b*CCH + cg*CPG)*PP;
  const int wid = tid>>6, lane = tid&63;
  const int ch0 = wid*64 + lane, ch1 = 256 + wid*64 + lane;

  #define STAGE(bsel, cc_) { \
    const float* gsrc = xg + (size_t)(cc_)*PP + src_row*HW; \
    if(ch0 < nchunks) gload16(gsrc + ch0*4, &xt[bsel][ldsoff + wid*256]); \
    if(ch1 < nchunks) gload16(gsrc + ch1*4, &xt[bsel][ldsoff + 1024 + wid*256]); }

  const int or_ = tid>>5, j0 = (tid&31)*5;

  __syncthreads();                  // zero-init + weights visible
  STAGE(0, 0);
  __syncthreads();                  // ch0 staged (vmcnt drained at barrier)

  float acc[3][5];
  #pragma unroll
  for(int o=0;o<3;o++)
    #pragma unroll
    for(int px=0;px<5;px++) acc[o][px]=0.f;

  int cur=0;
  for(int cc=0; cc<CPG; cc++){
    if(cc+1<CPG) STAGE(cur^1, cc+1);         // async DMA into other buffer
    float sv[3][7];
    #pragma unroll
    for(int rr=0;rr<3;rr++){
      const float* row = &xt[cur][(or_+rr)*HW];
      sv[rr][0] = (j0>0) ? row[j0-1] : 0.f;
      #pragma unroll
      for(int k=1;k<6;k++) sv[rr][k] = row[j0-1+k];
      sv[rr][6] = (j0+5<HW) ? row[j0+5] : 0.f;   // col 160 would wrap to next row
    }
    float s=0.f, s2=0.f;
    #pragma unroll
    for(int k=1;k<6;k++){ float vv=sv[1][k]; s+=vv; s2=fmaf(vv,vv,s2); }
    #pragma unroll
    for(int off=32; off; off>>=1){ s += __shfl_xor(s,off); s2 += __shfl_xor(s2,off); }
    if(lane==0){ bsA[cc][wid] += s; bsB[cc][wid] += s2; }
    #pragma unroll
    for(int o=0;o<3;o++){
      #pragma unroll
      for(int kr=0;kr<3;kr++){
        float w0 = wl[cc][o*9+kr*3+0];
        float w1 = wl[cc][o*9+kr*3+1];
        float w2 = wl[cc][o*9+kr*3+2];
        #pragma unroll
        for(int px=0;px<5;px++)
          acc[o][px] = fmaf(w0, sv[kr][px], fmaf(w1, sv[kr][px+1], fmaf(w2, sv[kr][px+2], acc[o][px])));
      }
    }
    __syncthreads();                // DMA for cc+1 landed; all reads of cur done
    cur ^= 1;
  }
  #undef STAGE

  if(tid < CPG){
    float a = bsA[tid][0]+bsA[tid][1]+bsA[tid][2]+bsA[tid][3];
    float bq = bsB[tid][0]+bsB[tid][1]+bsB[tid][2]+bsB[tid][3];
    atomicAdd(&sumA[cg*CPG+tid], (double)a);
    atomicAdd(&sumB[cg*CPG+tid], (double)bq);
  }
  size_t base = ((size_t)(cg*BB+b)*3)*PP + (size_t)(r0+or_)*HW + j0;
  #pragma unroll
  for(int o=0;o<3;o++){
    #pragma unroll
    for(int px=0;px<5;px++) partial[base + (size_t)o*PP + px] = acc[o][px];
  }
}

// ---------------- softmax + argmax + union-find init (fused) ----------------
__global__ void ksoftmax(const float* __restrict__ partial, const float* __restrict__ cb,
                         float* __restrict__ attn, u8* __restrict__ am,
                         int* __restrict__ parent, int* __restrict__ maxidx){
  int idx = blockIdx.x*256 + threadIdx.x;
  if(idx >= BB*PP) return;
  int b = idx/PP, p = idx%PP;
  float l[3];
  #pragma unroll
  for(int o=0;o<3;o++){
    float s = cb[o];
    #pragma unroll
    for(int cg=0;cg<NCG;cg++) s += partial[(((size_t)cg*BB+b)*3+o)*PP + p];
    l[o]=s;
  }
  int a=0; float best=l[0];
  if(l[1]>best){best=l[1];a=1;}
  if(l[2]>best){best=l[2];a=2;}
  float e0=__expf(l[0]-best);
  float e1=__expf(l[1]-best);
  float e2=__expf(l[2]-best);
  float inv = 1.f/(e0+e1+e2);
  attn[((size_t)b*3+0)*PP+p]=e0*inv;
  attn[((size_t)b*3+1)*PP+p]=e1*inv;
  attn[((size_t)b*3+2)*PP+p]=e2*inv;
  am[idx]=(u8)a;
  int i1 = (b*2+0)*PP + p, i2 = (b*2+1)*PP + p;
  parent[i1] = (a==1) ? p : -1;
  parent[i2] = (a==2) ? p : -1;
  maxidx[i1] = -1;
  maxidx[i2] = -1;
}

// ---------------- CCL: union-find ----------------
__device__ inline int froot(int* par, int x){
  while(true){
    int p = par[x];
    if(p == x) return x;
    int g = par[p];
    if(g == p) return p;
    par[x] = g;   // path halving (benign race)
    x = g;
  }
}
__device__ inline void unite(int* par, int a, int b){
  int ra = froot(par,a), rb = froot(par,b);
  while(ra != rb){
    if(ra > rb){ int t=ra; ra=rb; rb=t; }
    int old = atomicCAS(&par[rb], rb, ra);
    if(old == rb) return;
    rb = froot(par, old);
    ra = froot(par, ra);
  }
}
__global__ void kunion(int* parent){
  int idx = blockIdx.x*256 + threadIdx.x;
  if(idx >= NIMG*PP) return;
  int img = idx/PP, p = idx%PP;
  int* par = parent + img*PP;
  if(par[p] < 0) return;
  int i = p/HW, j = p%HW;
  if(j < HW-1 && par[p+1] >= 0) unite(par, p, p+1);
  if(i < HW-1 && par[p+HW] >= 0) unite(par, p, p+HW);
}
// flatten + per-root max flat index (fused)
__global__ void kflatmax(int* parent, int* __restrict__ maxidx){
  int idx = blockIdx.x*256 + threadIdx.x;
  if(idx >= NIMG*PP) return;
  int img = idx/PP, p = idx%PP;
  int* par = parent + img*PP;
  if(par[p] < 0) return;
  int r = froot(par, p);
  par[p] = r;
  atomicMax(&maxidx[img*PP + r], p);
}

// ---------------- compact roots (block-aggregated: 1 atomic per block) ----------------
__global__ void kcompact(const int* __restrict__ parent, const int* __restrict__ maxidx,
                         int* __restrict__ rootlist, int* __restrict__ ncomp){
  int idx = blockIdx.x*256 + threadIdx.x;
  int img = idx/PP, p = idx%PP;                 // block lies in one img (PP%256==0)
  bool isroot = (parent[idx] == p);
  u64 mask = __ballot(isroot);
  int lane = threadIdx.x & 63;
  int wid = threadIdx.x >> 6;
  __shared__ int wcnt[4];
  __shared__ int bbase;
  if(lane == 0) wcnt[wid] = __popcll(mask);
  __syncthreads();
  if(threadIdx.x == 0){
    int tot = wcnt[0]+wcnt[1]+wcnt[2]+wcnt[3];
    bbase = (tot>0) ? atomicAdd(&ncomp[img], tot) : 0;
  }
  __syncthreads();
  if(isroot){
    int mybase = bbase;
    for(int wv=0; wv<wid; wv++) mybase += wcnt[wv];
    mybase += __popcll(mask & ((lane==63)? ~0ull>>1 : ((1ull<<lane)-1)));
    rootlist[img*MAXC + mybase] = (maxidx[idx]<<16) | p;   // sort key: maxidx-major
  }
}

// ---------------- select up to (20 - bg) smallest-label components ----------------
__global__ __launch_bounds__(256) void kselect(const int* __restrict__ rootlist, const int* __restrict__ ncomp,
                        const int* __restrict__ parent,
                        int* __restrict__ selr, int* __restrict__ nsel){
  int img = blockIdx.x, t = threadIdx.x;
  __shared__ int sv[256];
  __shared__ int scnt[256];
  const int* par = parent + img*PP;
  int cnt=0;
  for(int p=t; p<PP; p+=256) cnt += (par[p]>=0) ? 1 : 0;
  scnt[t]=cnt; __syncthreads();
  for(int off=128; off; off>>=1){ if(t<off) scnt[t]+=scnt[t+off]; __syncthreads(); }
  int K = LIM - ((scnt[0] < PP) ? 1 : 0);   // background label 0 takes rank 0 if present
  int nr = ncomp[img];
  const int* rl = rootlist + img*MAXC;
  int prev = -1, n = 0;
  for(int k=0;k<K;k++){
    int best = 0x7fffffff;
    for(int q=t; q<nr; q+=256){ int v=rl[q]; if(v>prev && v<best) best=v; }
    sv[t]=best; __syncthreads();
    for(int off=128; off; off>>=1){
      if(t<off && sv[t+off]<sv[t]) sv[t]=sv[t+off];
      __syncthreads();
    }
    int bv = sv[0]; __syncthreads();
    if(bv == 0x7fffffff) break;
    if(t==0) selr[img*LIM+k] = bv & 0xffff;
    prev = bv; n = k+1;
  }
  if(t==0) nsel[img] = n;
}

// ---------------- per-pixel segment code + counts + selected-pixel list ----------------
__global__ void kseg(const u8* __restrict__ am, const int* __restrict__ parent,
                     const int* __restrict__ selr, const int* __restrict__ nsel,
                     u8* __restrict__ seg, int* __restrict__ cnts,
                     int* __restrict__ list, int* __restrict__ lcnt){
  int idx = blockIdx.x*256 + threadIdx.x;
  __shared__ int cl[40];
  if(threadIdx.x < 40) cl[threadIdx.x] = 0;
  __syncthreads();
  int b = idx/PP, p = idx%PP;
  int a = am[idx];
  int code = 40;
  if(a > 0){
    int img = b*2 + a - 1;
    int r = parent[img*PP + p];
    int n = nsel[img];
    for(int k=0;k<n;k++){
      if(selr[img*LIM + k] == r){ code = (a-1)*LIM + k; break; }
    }
  }
  seg[idx] = (u8)code;
  if(code < 40){
    atomicAdd(&cl[code], 1);
    int pos = atomicAdd(&lcnt[b], 1);
    list[b*PP + pos] = (code<<16) | p;          // p < 25600 < 65536
  }
  __syncthreads();
  if(threadIdx.x < 40 && cl[threadIdx.x] > 0) atomicAdd(&cnts[b*40 + threadIdx.x], cl[threadIdx.x]);
}

// ---------------- gather bins for selected pixels only ----------------
__global__ __launch_bounds__(256) void kbins2(const float* __restrict__ x, const int* __restrict__ list,
                                              const int* __restrict__ lcnt,
                                              float* __restrict__ binsA, float* __restrict__ binsB){
  const int b = blockIdx.y;
  const int n = lcnt[b];
  const int c = threadIdx.x;
  for(int e = blockIdx.x; e < n; e += gridDim.x){
    int ent = list[b*PP + e];
    int p = ent & 0xffff;
    int code = ent >> 16;
    float v = x[((size_t)b*CCH + c)*PP + p];
    atomicAdd(&binsA[((size_t)b*40 + code)*CCH + c], v);
    atomicAdd(&binsB[((size_t)b*40 + code)*CCH + c], v*v);
  }
}

// ---------------- per-batch M = m1 m2^T, factors (f64 magnitude-faithful) ----------------
__global__ __launch_bounds__(256) void kmult(const float* __restrict__ binsA, const int* __restrict__ cnts,
                       const int* __restrict__ nsel, double* __restrict__ multd,
                       float* __restrict__ multf){
  const int b = blockIdx.x, t = threadIdx.x;
  __shared__ float m1[LIM][CCH+1], m2[LIM][CCH+1];
  __shared__ float Ml[LIM*LIM];
  const int n1 = nsel[b*2+0], n2 = nsel[b*2+1];
  for(int k=0;k<LIM;k++){
    m1[k][t] = (k<n1) ? binsA[((size_t)b*40 + k)*CCH + t] / (float)cnts[b*40 + k] : 0.f;
    m2[k][t] = (k<n2) ? binsA[((size_t)b*40 + LIM + k)*CCH + t] / (float)cnts[b*40 + LIM + k] : 0.f;
  }
  __syncthreads();
  for(int pid=t; pid<LIM*LIM; pid+=256){
    int i = pid/LIM, j = pid%LIM;
    float d = 0.f;
    for(int c=0;c<CCH;c++) d += m1[i][c]*m2[j][c];
    Ml[pid] = 1.f + d;   // rows/cols for invalid comps are exactly 1
  }
  __syncthreads();
  if(t < LIM){
    double pr=1.0;
    for(int j=0;j<LIM;j++) pr *= (double)Ml[t*LIM+j];
    multd[b*40 + t] = pr;
    multf[b*40 + t] = (float)pr;        // may overflow to inf, like np-f32
  } else if(t>=64 && t<64+LIM){
    int j=t-64; double pr=1.0;
    for(int i=0;i<LIM;i++) pr *= (double)Ml[i*LIM+j];
    multd[b*40 + LIM + j] = pr;
    multf[b*40 + LIM + j] = (float)pr;
  }
}

// ---------------- BN scale/shift with float32-overflow semantics ----------------
__global__ void kscale(const float* __restrict__ binsA, const float* __restrict__ binsB,
                       const double* __restrict__ sumA, const double* __restrict__ sumB,
                       const double* __restrict__ multd, const float* __restrict__ gamma,
                       const float* __restrict__ beta, float* __restrict__ scale, float* __restrict__ shift){
  int c = threadIdx.x;
  double s = sumA[c], s2 = sumB[c];
  for(int b=0;b<BB;b++){
    for(int sc=0; sc<40; sc++){
      double f = multd[b*40+sc];
      s  += (f-1.0)   * (double)binsA[((size_t)b*40+sc)*CCH + c];
      s2 += (f*f-1.0) * (double)binsB[((size_t)b*40+sc)*CCH + c];
    }
  }
  const double N = (double)BB*PP;
  double mean = s/N;
  double devsq = s2 - N*mean*mean;     // = sum((x2 - mu)^2), exact-ish in f64
  bool ovf = !(devsq <= 3.3e38) || !(fabs(s) <= 3.3e38) || !(s2 < 1e300);
  if(ovf){
    scale[c] = 0.f;
    shift[c] = beta[c];
  } else {
    double var = devsq/N;
    double inv = 1.0 / sqrt(var + 1e-5);
    float scv = (float)inv * gamma[c];
    scale[c] = scv;
    shift[c] = beta[c] - (float)mean * scv;
  }
}

// ---------------- final write: out = x*f*scale + shift (scale==0 -> shift) ----------------
__global__ __launch_bounds__(256) void kout(const float* __restrict__ x, const u8* __restrict__ seg,
                      const float* __restrict__ multf, const float* __restrict__ scale,
                      const float* __restrict__ shift, float* __restrict__ out){
  size_t idx = ((size_t)blockIdx.x*256 + threadIdx.x)*4;
  int b = (int)(idx / ((size_t)CCH*PP));
  int c = (int)((idx / PP) % CCH);
  int p = (int)(idx % PP);
  __shared__ float fm[41];
  if(threadIdx.x <= 40) fm[threadIdx.x] = (threadIdx.x<40) ? multf[b*40 + threadIdx.x] : 1.f;
  __syncthreads();
  float sc = scale[c], sh = shift[c];
  float4 o;
  if(sc == 0.f){
    o.x = sh; o.y = sh; o.z = sh; o.w = sh;   // avoid inf*0 = nan
  } else {
    float4 xv = *(const float4*)(x + idx);
    uchar4 sv = *(const uchar4*)(seg + (size_t)b*PP + p);
    o.x = xv.x * fm[sv.x] * sc + sh;
    o.y = xv.y * fm[sv.y] * sc + sh;
    o.z = xv.z * fm[sv.z] * sc + sh;
    o.w = xv.w * fm[sv.w] * sc + sh;
  }
  *(float4*)(out + idx) = o;
}

extern "C" void kernel_launch(void* const* d_in, const int* in_sizes, int n_in,
                              void* d_out, int out_size, void* d_ws, size_t ws_size,
                              hipStream_t stream){
  (void)in_sizes; (void)n_in; (void)out_size; (void)ws_size;
  const float* x  = (const float*)d_in[0];
  const float* w  = (const float*)d_in[1];
  const float* cb = (const float*)d_in[2];
  const float* gamma = (const float*)d_in[3];
  const float* beta  = (const float*)d_in[4];
  float* out  = (float*)d_out;
  float* attn = out + (size_t)BB*CCH*PP;       // 52,428,800

  // big scratch lives in the (not-yet-written) xn region of d_out
  float* partial  = out;                       // 8*8*3*25600 = 4,915,200 floats
  int*   parent   = (int*)(out + 20000000);    // 409,600 ints
  int*   maxidx   = (int*)(out + 20500000);    // 409,600 ints
  u8*    am       = (u8*)(out + 21000000);     // 204,800 B
  float* binsA    = out + 21100000;            // 8*40*256
  float* binsB    = out + 21200000;
  int*   rootlist = (int*)(out + 21300000);    // 16*12800 ints
  int*   ncomp    = (int*)(out + 21600000);    // 16 ints
  int*   list     = (int*)(out + 21700000);    // 8*25600 ints
  int*   lcnt     = (int*)(out + 22000000);    // 8 ints
  double* sumA    = (double*)(out + 22100000); // 256 doubles (8B aligned: even float idx)
  double* sumB    = (double*)(out + 22101000);

  // K-kernel inputs live in ws (must survive while kout overwrites d_out)
  double* multd = (double*)d_ws;               // 320 doubles
  float* multf  = (float*)((char*)d_ws + 2560);
  float* scale  = multf + BB*40;
  float* shift  = scale + CCH;
  int* selr     = (int*)(shift + CCH);
  int* nsel     = selr + NIMG*LIM;
  int* cnts     = nsel + NIMG;
  u8* seg       = (u8*)(cnts + BB*40);         // 204,800 B

  kzero<<<dim3(320), dim3(256), 0, stream>>>(binsA, binsB, cnts, ncomp, sumA, sumB, lcnt);
  kconv<<<dim3(RT,NCG,BB), dim3(256), 0, stream>>>(x, w, partial, sumA, sumB);
  ksoftmax<<<dim3(800), dim3(256), 0, stream>>>(partial, cb, attn, am, parent, maxidx);
  kunion<<<dim3(1600), dim3(256), 0, stream>>>(parent);
  kflatmax<<<dim3(1600), dim3(256), 0, stream>>>(parent, maxidx);
  kcompact<<<dim3(1600), dim3(256), 0, stream>>>(parent, maxidx, rootlist, ncomp);
  kselect<<<dim3(NIMG), dim3(256), 0, stream>>>(rootlist, ncomp, parent, selr, nsel);
  kseg<<<dim3(800), dim3(256), 0, stream>>>(am, parent, selr, nsel, seg, cnts, list, lcnt);
  kbins2<<<dim3(64,BB), dim3(256), 0, stream>>>(x, list, lcnt, binsA, binsB);
  kmult<<<dim3(BB), dim3(256), 0, stream>>>(binsA, cnts, nsel, multd, multf);
  kscale<<<dim3(1), dim3(256), 0, stream>>>(binsA, binsB, sumA, sumB, multd, gamma, beta, scale, shift);
  kout<<<dim3(51200), dim3(256), 0, stream>>>(x, seg, multf, scale, shift, out);
}